// Round 1
// baseline (256.171 us; speedup 1.0000x reference)
//
#include <hip/hip_runtime.h>
#include <math.h>

#define DD 256
#define BB 8
#define SS 1024

// cos(2*pi*t) for t >= 0 via hardware v_cos (input in revolutions)
__device__ __forceinline__ float cos2pi(float t) {
    float f = t - floorf(t);
    return __builtin_amdgcn_cosf(f);
}

__global__ __launch_bounds__(256, 4)
void fused_hierddpm(const float* __restrict__ seq,
                    const float* __restrict__ M1, const float* __restrict__ P1,
                    const float* __restrict__ g1, const float* __restrict__ be1,
                    const float* __restrict__ M2, const float* __restrict__ P2,
                    const float* __restrict__ g2, const float* __restrict__ be2,
                    float* __restrict__ out)
{
    __shared__ float xs[BB][DD];      // layer input rows (residual source)
    __shared__ float xt[BB][DD];      // x_trans (post-LN)
    __shared__ float stats[BB][2];    // mu, rsig per batch row

    const int s   = blockIdx.x;
    const int tid = threadIdx.x;      // == output column i
    const float kf = (float)s;

    // ---- stage x[b, s, :] rows into LDS (coalesced: one row per pass)
    for (int u = tid; u < BB * DD; u += 256) {
        int b = u >> 8, j = u & 255;
        xs[b][j] = seq[((size_t)b * SS + s) * DD + j];
    }
    __syncthreads();

    for (int layer = 0; layer < 2; ++layer) {
        const float* M  = layer ? M2  : M1;
        const float* P  = layer ? P2  : P1;
        const float* g  = layer ? g2  : g1;
        const float* be = layer ? be2 : be1;

        // ---- x @ M.T : thread tid computes column i = tid for all 8 batch rows
        float m[BB];
        #pragma unroll
        for (int b = 0; b < BB; ++b) m[b] = 0.f;
        const float4* Mrow = (const float4*)(M + (size_t)tid * DD);
        #pragma unroll 4
        for (int j4 = 0; j4 < DD / 4; ++j4) {
            float4 mv = Mrow[j4];
            #pragma unroll
            for (int b = 0; b < BB; ++b) {
                float4 xv = ((const float4*)xs[b])[j4];   // LDS broadcast b128
                m[b] = fmaf(mv.x, xv.x, m[b]);
                m[b] = fmaf(mv.y, xv.y, m[b]);
                m[b] = fmaf(mv.z, xv.z, m[b]);
                m[b] = fmaf(mv.w, xv.w, m[b]);
            }
        }
        #pragma unroll
        for (int b = 0; b < BB; ++b) xt[b][tid] = m[b];
        __syncthreads();

        // ---- LayerNorm stats: wave w reduces batch rows 2w and 2w+1
        {
            int wave = tid >> 6;
            int lane = tid & 63;
            #pragma unroll
            for (int q = 0; q < 2; ++q) {
                int b = wave * 2 + q;
                float sum = 0.f, ssq = 0.f;
                #pragma unroll
                for (int r = 0; r < 4; ++r) {
                    float v = xt[b][lane + 64 * r];
                    sum += v;
                    ssq  = fmaf(v, v, ssq);
                }
                #pragma unroll
                for (int off = 32; off >= 1; off >>= 1) {
                    sum += __shfl_xor(sum, off, 64);
                    ssq += __shfl_xor(ssq, off, 64);
                }
                if (lane == 0) {
                    float mu  = sum * (1.f / DD);
                    float var = ssq * (1.f / DD) - mu * mu;
                    stats[b][0] = mu;
                    stats[b][1] = rsqrtf(var + 1e-5f);
                }
            }
        }
        __syncthreads();

        // ---- normalize in place
        {
            float gv = g[tid], bv = be[tid];
            #pragma unroll
            for (int b = 0; b < BB; ++b) {
                float mu = stats[b][0], rs = stats[b][1];
                xt[b][tid] = fmaf((xt[b][tid] - mu) * rs, gv, bv);
            }
        }
        __syncthreads();

        // ---- Nk[b, i] = sum_j xt[b][j] * P[i][j] * cos(2*pi*k / (i*256 + j + 2)),
        //      accumulated on top of residual xs[b][i]
        float acc[BB];
        #pragma unroll
        for (int b = 0; b < BB; ++b) acc[b] = xs[b][tid];

        const float4* Prow = (const float4*)(P + (size_t)tid * DD);
        const float pbase = (float)(tid * DD + 2);
        for (int j4 = 0; j4 < DD / 4; ++j4) {
            float4 pv = Prow[j4];
            float4 xv[BB];
            #pragma unroll
            for (int b = 0; b < BB; ++b)
                xv[b] = ((const float4*)xt[b])[j4];       // LDS broadcast b128

            float pj = pbase + (float)(4 * j4);
            float pw[4] = {pv.x, pv.y, pv.z, pv.w};
            #pragma unroll
            for (int jj = 0; jj < 4; ++jj) {
                float p = pj + (float)jj;
                float t = kf * __builtin_amdgcn_rcpf(p);  // k/p, ~1e-7 rel err
                float c = cos2pi(t);
                float w = pw[jj] * c;
                float xb[4];
                #pragma unroll
                for (int b = 0; b < BB; ++b) {
                    float xtv = (jj == 0) ? xv[b].x : (jj == 1) ? xv[b].y
                              : (jj == 2) ? xv[b].z : xv[b].w;
                    acc[b] = fmaf(w, xtv, acc[b]);
                }
                (void)xb;
            }
        }
        __syncthreads();   // all lanes done reading xt/xs before anyone rewrites

        if (layer == 0) {
            #pragma unroll
            for (int b = 0; b < BB; ++b) xs[b][tid] = acc[b];  // layer-1 output
            __syncthreads();
        } else {
            #pragma unroll
            for (int b = 0; b < BB; ++b)
                out[((size_t)b * SS + s) * DD + tid] = acc[b];
        }
    }
}

extern "C" void kernel_launch(void* const* d_in, const int* in_sizes, int n_in,
                              void* d_out, int out_size, void* d_ws, size_t ws_size,
                              hipStream_t stream)
{
    const float* seq = (const float*)d_in[0];
    const float* M1  = (const float*)d_in[1];
    const float* P1  = (const float*)d_in[2];
    const float* g1  = (const float*)d_in[3];
    const float* b1  = (const float*)d_in[4];
    const float* M2  = (const float*)d_in[5];
    const float* P2  = (const float*)d_in[6];
    const float* g2  = (const float*)d_in[7];
    const float* b2  = (const float*)d_in[8];
    float* out = (float*)d_out;

    fused_hierddpm<<<SS, 256, 0, stream>>>(seq, M1, P1, g1, b1,
                                           M2, P2, g2, b2, out);
}